// Round 8
// baseline (234.323 us; speedup 1.0000x reference)
//
#include <hip/hip_runtime.h>

// ---------------------------------------------------------------------------
// MultiHeadAttention (B=2, S=2048, D=1024, H=16, dk=64) on gfx950
// R12 = R11 with the x f32->bf16 conversion FUSED into qkv staging:
//  - qkv_fused reads q/k/v f32 directly; the f32 operand is register-staged
//    (f32x4 x2 -> cvt -> ds_write at the async-equivalent LDS address
//    At + ch0*512 + 8*lane), the bf16 weight operand keeps global_load_lds.
//  - cvt_all shrinks to weights-only (16MB read + 8MB write, was 64+32MB).
//  - Eliminates 48MB f32 read + 24MB bf16 write + 24MB bf16 re-read of HBM
//    traffic and one kernel boundary.
// flash_attn / out_proj are BYTE-IDENTICAL to R11 (one delta at a time).
// ---------------------------------------------------------------------------

typedef __bf16 bf16_8 __attribute__((ext_vector_type(8)));
typedef float  f32x4  __attribute__((ext_vector_type(4)));
typedef float  f32x16 __attribute__((ext_vector_type(16)));
typedef unsigned int u32x4 __attribute__((ext_vector_type(4)));

#define MFMA16(a, b, c) __builtin_amdgcn_mfma_f32_16x16x32_bf16((a), (b), (c), 0, 0, 0)
#define MFMA32(a, b, c) __builtin_amdgcn_mfma_f32_32x32x16_bf16((a), (b), (c), 0, 0, 0)

__device__ __forceinline__ void async_ld16(const void* g, void* l) {
  __builtin_amdgcn_global_load_lds(
      (__attribute__((address_space(1))) void*)g,
      (__attribute__((address_space(3))) void*)l, 16, 0, 0);
}

// ---------------------------------------------------------------------------
// 128x128 GEMM core, BK=32. Variant A-f32: A [MxK] f32 reg-staged+converted,
// BT [NxK] bf16 via global_load_lds. (m97 structure otherwise.)
// ---------------------------------------------------------------------------
__device__ __forceinline__ void gemm_core_128_af32(
    const float* __restrict__ A, const __bf16* __restrict__ BT, int K,
    int tm, int tn, __bf16* At, __bf16* Bt, f32x4 acc[4][4]) {
  const int tid  = threadIdx.x;
  const int lane = tid & 63;
  const int w    = tid >> 6;
  const int quad = lane >> 4;
  const int c16  = lane & 15;
  const int wm = w >> 1, wn = w & 1;

  const int ch0  = w * 2;
  const int row0 = ch0 * 16 + (lane >> 2);
  const int col0 = (lane & 3) * 8;
  const float*  Ag = A  + (size_t)(tm + row0) * K + col0;
  const __bf16* Bg = BT + (size_t)(tn + row0) * K + col0;
  // async contract: lane l writes At + ch0*512 + 8*l elements; mirror it.
  __bf16* Aw = At + ch0 * 512 + lane * 8;
  __bf16* Bl = Bt + ch0 * 512;
  const size_t rowK16 = (size_t)16 * K;

  for (int kt = 0; kt < K; kt += 32) {
    async_ld16(Bg + kt,          Bl);
    async_ld16(Bg + rowK16 + kt, Bl + 512);

    const f32x4 a00 = *(const f32x4*)(Ag + kt);
    const f32x4 a01 = *(const f32x4*)(Ag + kt + 4);
    const f32x4 a10 = *(const f32x4*)(Ag + rowK16 + kt);
    const f32x4 a11 = *(const f32x4*)(Ag + rowK16 + kt + 4);
    bf16_8 c0, c1;
#pragma unroll
    for (int i2 = 0; i2 < 4; ++i2) {
      c0[i2]     = (__bf16)a00[i2];
      c0[4 + i2] = (__bf16)a01[i2];
      c1[i2]     = (__bf16)a10[i2];
      c1[4 + i2] = (__bf16)a11[i2];
    }
    *(bf16_8*)Aw         = c0;
    *(bf16_8*)(Aw + 512) = c1;
    __syncthreads();

    bf16_8 af[4], bfr[4];
#pragma unroll
    for (int mi = 0; mi < 4; ++mi)
      af[mi] = *(const bf16_8*)(At + (wm * 64 + mi * 16 + c16) * 32 + quad * 8);
#pragma unroll
    for (int ni = 0; ni < 4; ++ni)
      bfr[ni] = *(const bf16_8*)(Bt + (wn * 64 + ni * 16 + c16) * 32 + quad * 8);
#pragma unroll
    for (int mi = 0; mi < 4; ++mi)
#pragma unroll
      for (int ni = 0; ni < 4; ++ni)
        acc[mi][ni] = MFMA16(af[mi], bfr[ni], acc[mi][ni]);
    __syncthreads();
  }
}

// ---------------------------------------------------------------------------
// Variant B-f32: A bf16 via global_load_lds, BT f32 reg-staged+converted.
// ---------------------------------------------------------------------------
__device__ __forceinline__ void gemm_core_128_bf32(
    const __bf16* __restrict__ A, const float* __restrict__ BT, int K,
    int tm, int tn, __bf16* At, __bf16* Bt, f32x4 acc[4][4]) {
  const int tid  = threadIdx.x;
  const int lane = tid & 63;
  const int w    = tid >> 6;
  const int quad = lane >> 4;
  const int c16  = lane & 15;
  const int wm = w >> 1, wn = w & 1;

  const int ch0  = w * 2;
  const int row0 = ch0 * 16 + (lane >> 2);
  const int col0 = (lane & 3) * 8;
  const __bf16* Ag = A  + (size_t)(tm + row0) * K + col0;
  const float*  Bg = BT + (size_t)(tn + row0) * K + col0;
  __bf16* Al = At + ch0 * 512;
  __bf16* Bw = Bt + ch0 * 512 + lane * 8;
  const size_t rowK16 = (size_t)16 * K;

  for (int kt = 0; kt < K; kt += 32) {
    async_ld16(Ag + kt,          Al);
    async_ld16(Ag + rowK16 + kt, Al + 512);

    const f32x4 b00 = *(const f32x4*)(Bg + kt);
    const f32x4 b01 = *(const f32x4*)(Bg + kt + 4);
    const f32x4 b10 = *(const f32x4*)(Bg + rowK16 + kt);
    const f32x4 b11 = *(const f32x4*)(Bg + rowK16 + kt + 4);
    bf16_8 c0, c1;
#pragma unroll
    for (int i2 = 0; i2 < 4; ++i2) {
      c0[i2]     = (__bf16)b00[i2];
      c0[4 + i2] = (__bf16)b01[i2];
      c1[i2]     = (__bf16)b10[i2];
      c1[4 + i2] = (__bf16)b11[i2];
    }
    *(bf16_8*)Bw         = c0;
    *(bf16_8*)(Bw + 512) = c1;
    __syncthreads();

    bf16_8 af[4], bfr[4];
#pragma unroll
    for (int mi = 0; mi < 4; ++mi)
      af[mi] = *(const bf16_8*)(At + (wm * 64 + mi * 16 + c16) * 32 + quad * 8);
#pragma unroll
    for (int ni = 0; ni < 4; ++ni)
      bfr[ni] = *(const bf16_8*)(Bt + (wn * 64 + ni * 16 + c16) * 32 + quad * 8);
#pragma unroll
    for (int mi = 0; mi < 4; ++mi)
#pragma unroll
      for (int ni = 0; ni < 4; ++ni)
        acc[mi][ni] = MFMA16(af[mi], bfr[ni], acc[mi][ni]);
    __syncthreads();
  }
}

// ---------------------------------------------------------------------------
// Original all-bf16 core (used by out_proj).
// ---------------------------------------------------------------------------
__device__ __forceinline__ void gemm_core_128(
    const __bf16* __restrict__ A, const __bf16* __restrict__ BT, int K,
    int tm, int tn, __bf16* At, __bf16* Bt, f32x4 acc[4][4]) {
  const int tid  = threadIdx.x;
  const int lane = tid & 63;
  const int w    = tid >> 6;
  const int quad = lane >> 4;
  const int c16  = lane & 15;
  const int wm = w >> 1, wn = w & 1;

  const int ch0  = w * 2;
  const int row0 = ch0 * 16 + (lane >> 2);
  const int col0 = (lane & 3) * 8;
  const __bf16* Ag = A  + (size_t)(tm + row0) * K + col0;
  const __bf16* Bg = BT + (size_t)(tn + row0) * K + col0;
  __bf16* Al = At + ch0 * 512;
  __bf16* Bl = Bt + ch0 * 512;
  const size_t rowK16 = (size_t)16 * K;

  for (int kt = 0; kt < K; kt += 32) {
    async_ld16(Ag + kt,          Al);
    async_ld16(Ag + rowK16 + kt, Al + 512);
    async_ld16(Bg + kt,          Bl);
    async_ld16(Bg + rowK16 + kt, Bl + 512);
    __syncthreads();

    bf16_8 af[4], bfr[4];
#pragma unroll
    for (int mi = 0; mi < 4; ++mi)
      af[mi] = *(const bf16_8*)(At + (wm * 64 + mi * 16 + c16) * 32 + quad * 8);
#pragma unroll
    for (int ni = 0; ni < 4; ++ni)
      bfr[ni] = *(const bf16_8*)(Bt + (wn * 64 + ni * 16 + c16) * 32 + quad * 8);
#pragma unroll
    for (int mi = 0; mi < 4; ++mi)
#pragma unroll
      for (int ni = 0; ni < 4; ++ni)
        acc[mi][ni] = MFMA16(af[mi], bfr[ni], acc[mi][ni]);
    __syncthreads();
  }
}

// ---------------------------------------------------------------------------
// Fused QKV projection, f32 activations in. grid = (256,1,3).
// V produced transposed [B,H,64,S]. Q pre-scaled by 0.125*log2e.
// ---------------------------------------------------------------------------
__global__ __launch_bounds__(256)
void qkv_fused(const float* __restrict__ xqf, const float* __restrict__ xkf,
               const float* __restrict__ xvf,
               const __bf16* __restrict__ wq, const __bf16* __restrict__ wk,
               const __bf16* __restrict__ wv,
               const float* __restrict__ bq, const float* __restrict__ bk,
               const float* __restrict__ bv,
               __bf16* __restrict__ Qo, __bf16* __restrict__ Ko,
               __bf16* __restrict__ Vo) {
  __shared__ __bf16 At[128 * 32];
  __shared__ __bf16 Bt[128 * 32];
  const int z  = blockIdx.z;
  const int bx = blockIdx.x;

  f32x4 acc[4][4];
  const f32x4 zero4 = {0.f, 0.f, 0.f, 0.f};
#pragma unroll
  for (int i = 0; i < 4; ++i)
#pragma unroll
    for (int j = 0; j < 4; ++j) acc[i][j] = zero4;

  const int lane = threadIdx.x & 63;
  const int w    = threadIdx.x >> 6;
  const int quad = lane >> 4, c16 = lane & 15;
  const int wm = w >> 1, wn = w & 1;

  if (z == 2) {        // V^T: M=1024 feats (wv), N=4096 tokens (v f32)
    const int tm = (bx >> 5) * 128, tn = (bx & 31) * 128;
    gemm_core_128_bf32(wv, xvf, 1024, tm, tn, At, Bt, acc);
#pragma unroll
    for (int mi = 0; mi < 4; ++mi) {
#pragma unroll
      for (int ni = 0; ni < 4; ++ni) {
        const int n  = tn + wn * 64 + ni * 16 + c16;  // token
        const int bb = n >> 11, s = n & 2047;
#pragma unroll
        for (int r = 0; r < 4; ++r) {
          const int m  = tm + wm * 64 + mi * 16 + quad * 4 + r;  // feature
          const int hh = m >> 6, d = m & 63;
          Vo[(((size_t)(bb * 16 + hh) * 64 + d) << 11) + s] =
              (__bf16)(acc[mi][ni][r] + bv[m]);
        }
      }
    }
  } else {             // Q/K: M=4096 tokens (x f32), N=1024 feats (w)
    const int tm = (bx >> 3) * 128, tn = (bx & 7) * 128;
    const float*  A  = z ? xkf : xqf;
    const __bf16* BT = z ? wk : wq;
    const float*  bias = z ? bk : bq;
    gemm_core_128_af32(A, BT, 1024, tm, tn, At, Bt, acc);

    __bf16* Out = z ? Ko : Qo;
    const float scale = (z == 0) ? 0.1803368801f : 1.0f;  // 0.125 * log2(e)
#pragma unroll
    for (int mi = 0; mi < 4; ++mi) {
#pragma unroll
      for (int ni = 0; ni < 4; ++ni) {
        const int n  = tn + wn * 64 + ni * 16 + c16;  // feature
        const int hh = n >> 6, d = n & 63;
        const float bn = bias[n];
#pragma unroll
        for (int r = 0; r < 4; ++r) {
          const int m  = tm + wm * 64 + mi * 16 + quad * 4 + r;  // token
          const int bb = m >> 11, s = m & 2047;
          Out[(((size_t)(bb * 16 + hh) * 2048 + s) << 6) + d] =
              (__bf16)((acc[mi][ni][r] + bn) * scale);
        }
      }
    }
  }
}

// ---------------------------------------------------------------------------
// Output projection, 64x128 tile -> 512 blocks (2 blocks/CU). (R11/R5 form.)
// ---------------------------------------------------------------------------
__global__ __launch_bounds__(256)
void out_proj(const __bf16* __restrict__ ctx, const __bf16* __restrict__ wo,
              const float* __restrict__ bo, float* __restrict__ out) {
  __shared__ __bf16 At[64 * 32];
  __shared__ __bf16 Bt[128 * 32];
  const int bx = blockIdx.x;
  const int tm = (bx >> 3) * 64, tn = (bx & 7) * 128;

  const int tid  = threadIdx.x;
  const int lane = tid & 63, w = tid >> 6;
  const int quad = lane >> 4, c16 = lane & 15;
  const int wm = w >> 1, wn = w & 1;

  const int row0 = lane >> 2, col0 = (lane & 3) * 8;
  const __bf16* Ag = ctx + (size_t)(tm + w * 16 + row0) * 1024 + col0;
  const __bf16* Bg = wo  + (size_t)(tn + w * 32 + row0) * 1024 + col0;
  __bf16* Al = At + w * 512;
  __bf16* Bl = Bt + w * 1024;

  f32x4 acc[2][4];
  const f32x4 zero4 = {0.f, 0.f, 0.f, 0.f};
#pragma unroll
  for (int i = 0; i < 2; ++i)
#pragma unroll
    for (int j = 0; j < 4; ++j) acc[i][j] = zero4;

  for (int kt = 0; kt < 1024; kt += 32) {
    async_ld16(Ag + kt, Al);
    async_ld16(Bg + kt, Bl);
    async_ld16(Bg + 16 * 1024 + kt, Bl + 512);
    __syncthreads();

    bf16_8 af[2], bfr[4];
#pragma unroll
    for (int mi = 0; mi < 2; ++mi)
      af[mi] = *(const bf16_8*)(At + (wm * 32 + mi * 16 + c16) * 32 + quad * 8);
#pragma unroll
    for (int ni = 0; ni < 4; ++ni)
      bfr[ni] = *(const bf16_8*)(Bt + (wn * 64 + ni * 16 + c16) * 32 + quad * 8);
#pragma unroll
    for (int mi = 0; mi < 2; ++mi)
#pragma unroll
      for (int ni = 0; ni < 4; ++ni)
        acc[mi][ni] = MFMA16(af[mi], bfr[ni], acc[mi][ni]);
    __syncthreads();
  }

#pragma unroll
  for (int mi = 0; mi < 2; ++mi) {
#pragma unroll
    for (int ni = 0; ni < 4; ++ni) {
      const int n = tn + wn * 64 + ni * 16 + c16;
      const float bn = bo[n];
#pragma unroll
      for (int r = 0; r < 4; ++r) {
        const int m = tm + wm * 32 + mi * 16 + quad * 4 + r;
        out[(size_t)m * 1024 + n] = acc[mi][ni][r] + bn;
      }
    }
  }
}

// ---------------------------------------------------------------------------
// Flash attention — BYTE-IDENTICAL to R11 (KVBLK=128, seed/exp2, 52.7 us).
// ---------------------------------------------------------------------------
__global__ __launch_bounds__(512, 4)
void flash_attn(const __bf16* __restrict__ Qg, const __bf16* __restrict__ Kg,
                const __bf16* __restrict__ VTg, const int* __restrict__ maskg,
                __bf16* __restrict__ ctx) {
  __shared__ __align__(16) char smem_[73216];

  const int t    = threadIdx.x;
  const int lane = t & 63;
  const int w    = t >> 6;
  const int g    = w & 3;    // q-group (32 rows)
  const int hh   = w >> 2;   // kv half
  const int n32  = lane & 31;
  const int h    = lane >> 5;

  // XCD swizzle: 512 blocks = 8 XCDs x 64; chunk so one XCD sees 4 heads' KV.
  const int linear = blockIdx.x + (blockIdx.y << 4) + (blockIdx.z << 8);
  const int sw     = (linear & 7) * 64 + (linear >> 3);
  const int qt     = sw & 15;
  const int head   = (sw >> 4) & 15;
  const int b      = sw >> 8;

  const size_t bh = (size_t)(b * 16 + head);
  const int qbase = qt * 128 + g * 32;

  // Q b-frags (B-operand: lane&31 = q row, k-chunk by lane>>5). Pre-scaled
  // by 0.125*log2e, so QK^T lands directly in the log2 domain.
  bf16_8 bq[4];
  {
    const __bf16* qptr = Qg + (bh * 2048 + qbase + n32) * 64 + h * 8;
#pragma unroll
    for (int s = 0; s < 4; ++s) bq[s] = *(const bf16_8*)(qptr + s * 16);
  }

  const f32x16 z16 = {0.f,0.f,0.f,0.f,0.f,0.f,0.f,0.f,
                      0.f,0.f,0.f,0.f,0.f,0.f,0.f,0.f};
  f32x16 o0 = z16, o1 = z16;   // O[32q x 64d]: dt=0,1
  float lsum = 0.f;

  // per-half LDS views (addresses loop-invariant)
  __bf16* const Kl = (__bf16*)smem_           + hh * (128 * 72);
  __bf16* const Vl = (__bf16*)(smem_ + 36864) + hh * (64 * 136);
  float*  const Ml = (float*)(smem_ + 71680)  + hh * 128;

  // staging: threads 0-255 stage half 0, 256-511 half 1 (hh == t>>8)
  const int tl   = t & 255;
  const int srow = tl >> 2, scc = (tl & 3) * 16;
  const __bf16* Kgp = Kg  + (bh * 2048 + hh * 1024) * 64;
  const __bf16* Vgp = VTg + bh * 64 * 2048 + hh * 1024;
  const int*    mgp = maskg + b * 2048 + hh * 1024;

  for (int ktb = 0; ktb < 1024; ktb += 128) {
    // stage 128 keys: K rows [ktb, ktb+128) and V^T cols [ktb, ktb+128)
#pragma unroll
    for (int r2 = 0; r2 < 2; ++r2) {
      const size_t kb = (size_t)(ktb + r2 * 64 + srow) * 64 + scc;
      __bf16* kw = Kl + (r2 * 64 + srow) * 72 + scc;
      *(bf16_8*)kw       = *(const bf16_8*)&Kgp[kb];
      *(bf16_8*)(kw + 8) = *(const bf16_8*)&Kgp[kb + 8];
      const size_t vb = (size_t)srow * 2048 + ktb + r2 * 64 + scc;
      __bf16* vw = Vl + srow * 136 + r2 * 64 + scc;
      *(bf16_8*)vw       = *(const bf16_8*)&Vgp[vb];
      *(bf16_8*)(vw + 8) = *(const bf16_8*)&Vgp[vb + 8];
    }
    if (tl < 128) Ml[tl] = mgp[ktb + tl] ? -17.3123404907f : -1e30f;
    __syncthreads();

#pragma unroll
    for (int kt2 = 0; kt2 < 4; ++kt2) {
      // S^T = K · Q^T, accumulator SEEDED with the log2-domain mask additive:
      // p[4j+e] needs maskadd[kt2*32 + e + 8j + 4h]
      f32x16 p;
#pragma unroll
      for (int j = 0; j < 4; ++j) {
        const f32x4 m4 = *(const f32x4*)&Ml[kt2 * 32 + 8 * j + 4 * h];
        p[4 * j + 0] = m4[0];
        p[4 * j + 1] = m4[1];
        p[4 * j + 2] = m4[2];
        p[4 * j + 3] = m4[3];
      }
#pragma unroll
      for (int s = 0; s < 4; ++s) {
        const bf16_8 ka =
            *(const bf16_8*)&Kl[(kt2 * 32 + n32) * 72 + s * 16 + h * 8];
        p = MFMA32(ka, bq[s], p);
      }

      // softmax: bare exp2 (Q carried log2e; mask & -12 shift already in p)
      unsigned c[8];
#pragma unroll
      for (int i = 0; i < 8; ++i) {
        const float e0 = __builtin_amdgcn_exp2f(p[2 * i]);
        const float e1 = __builtin_amdgcn_exp2f(p[2 * i + 1]);
        lsum += e0 + e1;
        union { __bf16 hx[2]; unsigned u; } uu;
        uu.hx[0] = (__bf16)e0;
        uu.hx[1] = (__bf16)e1;
        c[i] = uu.u;
      }
      // redistribute to PV A-frag layout
      asm volatile("v_permlane32_swap_b32 %0, %1" : "+v"(c[0]), "+v"(c[2]));
      asm volatile("v_permlane32_swap_b32 %0, %1" : "+v"(c[1]), "+v"(c[3]));
      asm volatile("v_permlane32_swap_b32 %0, %1" : "+v"(c[4]), "+v"(c[6]));
      asm volatile("v_permlane32_swap_b32 %0, %1" : "+v"(c[5]), "+v"(c[7]));

#pragma unroll
      for (int sub = 0; sub < 2; ++sub) {
        const u32x4 av = {c[4 * sub + 0], c[4 * sub + 1],
                          c[4 * sub + 2], c[4 * sub + 3]};
        const bf16_8 aP = __builtin_bit_cast(bf16_8, av);
        const int s = kt2 * 2 + sub;   // k-slot within the 128-key tile
        const bf16_8 vb0 =
            *(const bf16_8*)&Vl[n32 * 136 + s * 16 + h * 8];
        const bf16_8 vb1 =
            *(const bf16_8*)&Vl[(32 + n32) * 136 + s * 16 + h * 8];
        o0 = MFMA32(aP, vb0, o0);
        o1 = MFMA32(aP, vb1, o1);
      }
    }
    __syncthreads();
  }

  // full row-sum over this wave's kv-half (lane's two k subsets are disjoint)
  lsum += __shfl_xor(lsum, 32);

  float (*Om)[32][64] = (float(*)[32][64])smem_;          // overlays staging
  float (*Lm)[32]     = (float(*)[32])(smem_ + 72704);

  if (hh) {  // upper half: publish partials
#pragma unroll
    for (int r = 0; r < 16; ++r) {
      const int qrow = (r & 3) + 8 * (r >> 2) + 4 * h;
      Om[g][qrow][n32]      = o0[r];
      Om[g][qrow][32 + n32] = o1[r];
    }
    if (h == 0) Lm[g][n32] = lsum;
  }
  __syncthreads();
  if (!hh) {  // lower half: merge, normalize, store
    const float linv = 1.0f / (lsum + Lm[g][n32]);
#pragma unroll
    for (int r = 0; r < 16; ++r) {
      const int qrow = (r & 3) + 8 * (r >> 2) + 4 * h;
      const float li = __shfl(linv, qrow);
      __bf16* cp = ctx + ((size_t)b * 2048 + qbase + qrow) * 1024 + head * 64;
      cp[n32]      = (__bf16)((o0[r] + Om[g][qrow][n32]) * li);
      cp[32 + n32] = (__bf16)((o1[r] + Om[g][qrow][32 + n32]) * li);
    }
  }
}

// ---------------------------------------------------------------------------
// weights-only f32 -> bf16 converter: 4 x [1024x1024]. grid (512,4)x256.
// ---------------------------------------------------------------------------
__global__ __launch_bounds__(256)
void cvt_w(const float* __restrict__ Wq, const float* __restrict__ Wk,
           const float* __restrict__ Wv, const float* __restrict__ Wo,
           __bf16* __restrict__ wqb, __bf16* __restrict__ wkb,
           __bf16* __restrict__ wvb, __bf16* __restrict__ wob) {
  const int y = blockIdx.y;
  const float* s;
  __bf16* d;
  switch (y) {
    case 0:  s = Wq; d = wqb; break;
    case 1:  s = Wk; d = wkb; break;
    case 2:  s = Wv; d = wvb; break;
    default: s = Wo; d = wob; break;
  }
  const int i = blockIdx.x * blockDim.x + threadIdx.x;  // exactly 131072/y
  const float4* sp = (const float4*)s;
  const float4 v0 = sp[i * 2], v1 = sp[i * 2 + 1];
  bf16_8 o;
  o[0] = (__bf16)v0.x; o[1] = (__bf16)v0.y;
  o[2] = (__bf16)v0.z; o[3] = (__bf16)v0.w;
  o[4] = (__bf16)v1.x; o[5] = (__bf16)v1.y;
  o[6] = (__bf16)v1.z; o[7] = (__bf16)v1.w;
  *(bf16_8*)(d + (size_t)i * 8) = o;
}

// ---------------------------------------------------------------------------
extern "C" void kernel_launch(void* const* d_in, const int* in_sizes, int n_in,
                              void* d_out, int out_size, void* d_ws, size_t ws_size,
                              hipStream_t stream) {
  (void)in_sizes; (void)n_in; (void)out_size; (void)ws_size;
  const float* q    = (const float*)d_in[0];
  const float* k    = (const float*)d_in[1];
  const float* v    = (const float*)d_in[2];
  const int*   mask = (const int*)d_in[3];
  const float* Wq = (const float*)d_in[4];
  const float* bq = (const float*)d_in[5];
  const float* Wk = (const float*)d_in[6];
  const float* bk = (const float*)d_in[7];
  const float* Wv = (const float*)d_in[8];
  const float* bv = (const float*)d_in[9];
  const float* Wo = (const float*)d_in[10];
  const float* bo = (const float*)d_in[11];

  char* ws = (char*)d_ws;
  const size_t MB = 1ull << 20;
  __bf16* wqb = (__bf16*)(ws + 24 * MB);
  __bf16* wkb = (__bf16*)(ws + 26 * MB);
  __bf16* wvb = (__bf16*)(ws + 28 * MB);
  __bf16* wob = (__bf16*)(ws + 30 * MB);
  __bf16* Qb  = (__bf16*)(ws + 32 * MB);
  __bf16* Kb  = (__bf16*)(ws + 40 * MB);
  __bf16* VTb = (__bf16*)(ws + 48 * MB);
  __bf16* ctx = (__bf16*)(ws + 56 * MB);

  cvt_w<<<dim3(512, 4), 256, 0, stream>>>(Wq, Wk, Wv, Wo,
                                          wqb, wkb, wvb, wob);

  qkv_fused<<<dim3(256, 1, 3), 256, 0, stream>>>(q, k, v, wqb, wkb, wvb,
                                                 bq, bk, bv, Qb, Kb, VTb);

  flash_attn<<<dim3(16, 16, 2), 512, 0, stream>>>(Qb, Kb, VTb, mask, ctx);

  out_proj<<<dim3(512), 256, 0, stream>>>(ctx, wob, bo, (float*)d_out);
}

// Round 9
// 222.298 us; speedup vs baseline: 1.0541x; 1.0541x over previous
//
#include <hip/hip_runtime.h>

// ---------------------------------------------------------------------------
// MultiHeadAttention (B=2, S=2048, D=1024, H=16, dk=64) on gfx950
// R13 = R12 + XCD-chunk swizzles ONLY (T1; regime now fetch-bound so the
// mechanism applies — R7's null was in the non-fetch-bound bf16 regime):
//  - qkv z0/z1: bx chunked so the 8 blocks sharing one f32 activation panel
//    co-reside on one XCD (panel re-fetch 8x -> 1x).
//  - qkv z2: decomposition flipped (tm=bx&7, tn=bx>>3) so f32 token panels
//    are XCD-exclusive and small wv panels broadcast.
//  - out_proj: same chunking (512 = 8 XCDs x 64), ctx panels XCD-exclusive.
// flash_attn BYTE-IDENTICAL to R11/R12 (52.7 us verified).
// ---------------------------------------------------------------------------

typedef __bf16 bf16_8 __attribute__((ext_vector_type(8)));
typedef float  f32x4  __attribute__((ext_vector_type(4)));
typedef float  f32x16 __attribute__((ext_vector_type(16)));
typedef unsigned int u32x4 __attribute__((ext_vector_type(4)));

#define MFMA16(a, b, c) __builtin_amdgcn_mfma_f32_16x16x32_bf16((a), (b), (c), 0, 0, 0)
#define MFMA32(a, b, c) __builtin_amdgcn_mfma_f32_32x32x16_bf16((a), (b), (c), 0, 0, 0)

__device__ __forceinline__ void async_ld16(const void* g, void* l) {
  __builtin_amdgcn_global_load_lds(
      (__attribute__((address_space(1))) void*)g,
      (__attribute__((address_space(3))) void*)l, 16, 0, 0);
}

// ---------------------------------------------------------------------------
// 128x128 GEMM core, BK=32. Variant A-f32: A [MxK] f32 reg-staged+converted,
// BT [NxK] bf16 via global_load_lds. (m97 structure otherwise.)
// ---------------------------------------------------------------------------
__device__ __forceinline__ void gemm_core_128_af32(
    const float* __restrict__ A, const __bf16* __restrict__ BT, int K,
    int tm, int tn, __bf16* At, __bf16* Bt, f32x4 acc[4][4]) {
  const int tid  = threadIdx.x;
  const int lane = tid & 63;
  const int w    = tid >> 6;
  const int quad = lane >> 4;
  const int c16  = lane & 15;
  const int wm = w >> 1, wn = w & 1;

  const int ch0  = w * 2;
  const int row0 = ch0 * 16 + (lane >> 2);
  const int col0 = (lane & 3) * 8;
  const float*  Ag = A  + (size_t)(tm + row0) * K + col0;
  const __bf16* Bg = BT + (size_t)(tn + row0) * K + col0;
  // async contract: lane l writes At + ch0*512 + 8*l elements; mirror it.
  __bf16* Aw = At + ch0 * 512 + lane * 8;
  __bf16* Bl = Bt + ch0 * 512;
  const size_t rowK16 = (size_t)16 * K;

  for (int kt = 0; kt < K; kt += 32) {
    async_ld16(Bg + kt,          Bl);
    async_ld16(Bg + rowK16 + kt, Bl + 512);

    const f32x4 a00 = *(const f32x4*)(Ag + kt);
    const f32x4 a01 = *(const f32x4*)(Ag + kt + 4);
    const f32x4 a10 = *(const f32x4*)(Ag + rowK16 + kt);
    const f32x4 a11 = *(const f32x4*)(Ag + rowK16 + kt + 4);
    bf16_8 c0, c1;
#pragma unroll
    for (int i2 = 0; i2 < 4; ++i2) {
      c0[i2]     = (__bf16)a00[i2];
      c0[4 + i2] = (__bf16)a01[i2];
      c1[i2]     = (__bf16)a10[i2];
      c1[4 + i2] = (__bf16)a11[i2];
    }
    *(bf16_8*)Aw         = c0;
    *(bf16_8*)(Aw + 512) = c1;
    __syncthreads();

    bf16_8 af[4], bfr[4];
#pragma unroll
    for (int mi = 0; mi < 4; ++mi)
      af[mi] = *(const bf16_8*)(At + (wm * 64 + mi * 16 + c16) * 32 + quad * 8);
#pragma unroll
    for (int ni = 0; ni < 4; ++ni)
      bfr[ni] = *(const bf16_8*)(Bt + (wn * 64 + ni * 16 + c16) * 32 + quad * 8);
#pragma unroll
    for (int mi = 0; mi < 4; ++mi)
#pragma unroll
      for (int ni = 0; ni < 4; ++ni)
        acc[mi][ni] = MFMA16(af[mi], bfr[ni], acc[mi][ni]);
    __syncthreads();
  }
}

// ---------------------------------------------------------------------------
// Variant B-f32: A bf16 via global_load_lds, BT f32 reg-staged+converted.
// ---------------------------------------------------------------------------
__device__ __forceinline__ void gemm_core_128_bf32(
    const __bf16* __restrict__ A, const float* __restrict__ BT, int K,
    int tm, int tn, __bf16* At, __bf16* Bt, f32x4 acc[4][4]) {
  const int tid  = threadIdx.x;
  const int lane = tid & 63;
  const int w    = tid >> 6;
  const int quad = lane >> 4;
  const int c16  = lane & 15;
  const int wm = w >> 1, wn = w & 1;

  const int ch0  = w * 2;
  const int row0 = ch0 * 16 + (lane >> 2);
  const int col0 = (lane & 3) * 8;
  const __bf16* Ag = A  + (size_t)(tm + row0) * K + col0;
  const float*  Bg = BT + (size_t)(tn + row0) * K + col0;
  __bf16* Al = At + ch0 * 512;
  __bf16* Bw = Bt + ch0 * 512 + lane * 8;
  const size_t rowK16 = (size_t)16 * K;

  for (int kt = 0; kt < K; kt += 32) {
    async_ld16(Ag + kt,          Al);
    async_ld16(Ag + rowK16 + kt, Al + 512);

    const f32x4 b00 = *(const f32x4*)(Bg + kt);
    const f32x4 b01 = *(const f32x4*)(Bg + kt + 4);
    const f32x4 b10 = *(const f32x4*)(Bg + rowK16 + kt);
    const f32x4 b11 = *(const f32x4*)(Bg + rowK16 + kt + 4);
    bf16_8 c0, c1;
#pragma unroll
    for (int i2 = 0; i2 < 4; ++i2) {
      c0[i2]     = (__bf16)b00[i2];
      c0[4 + i2] = (__bf16)b01[i2];
      c1[i2]     = (__bf16)b10[i2];
      c1[4 + i2] = (__bf16)b11[i2];
    }
    *(bf16_8*)Bw         = c0;
    *(bf16_8*)(Bw + 512) = c1;
    __syncthreads();

    bf16_8 af[4], bfr[4];
#pragma unroll
    for (int mi = 0; mi < 4; ++mi)
      af[mi] = *(const bf16_8*)(At + (wm * 64 + mi * 16 + c16) * 32 + quad * 8);
#pragma unroll
    for (int ni = 0; ni < 4; ++ni)
      bfr[ni] = *(const bf16_8*)(Bt + (wn * 64 + ni * 16 + c16) * 32 + quad * 8);
#pragma unroll
    for (int mi = 0; mi < 4; ++mi)
#pragma unroll
      for (int ni = 0; ni < 4; ++ni)
        acc[mi][ni] = MFMA16(af[mi], bfr[ni], acc[mi][ni]);
    __syncthreads();
  }
}

// ---------------------------------------------------------------------------
// Fused QKV projection, f32 activations in. grid = (256,1,3).
// V produced transposed [B,H,64,S]. Q pre-scaled by 0.125*log2e.
// XCD-chunk swizzle: the 8 blocks sharing an f32 panel co-reside on one XCD.
// ---------------------------------------------------------------------------
__global__ __launch_bounds__(256)
void qkv_fused(const float* __restrict__ xqf, const float* __restrict__ xkf,
               const float* __restrict__ xvf,
               const __bf16* __restrict__ wq, const __bf16* __restrict__ wk,
               const __bf16* __restrict__ wv,
               const float* __restrict__ bq, const float* __restrict__ bk,
               const float* __restrict__ bv,
               __bf16* __restrict__ Qo, __bf16* __restrict__ Ko,
               __bf16* __restrict__ Vo) {
  __shared__ __bf16 At[128 * 32];
  __shared__ __bf16 Bt[128 * 32];
  const int z   = blockIdx.z;
  const int bx0 = blockIdx.x;
  // XCD chunk: XCD x (= bx0 % 8) gets the contiguous range [x*32, x*32+32).
  const int bx  = (bx0 & 7) * 32 + (bx0 >> 3);

  f32x4 acc[4][4];
  const f32x4 zero4 = {0.f, 0.f, 0.f, 0.f};
#pragma unroll
  for (int i = 0; i < 4; ++i)
#pragma unroll
    for (int j = 0; j < 4; ++j) acc[i][j] = zero4;

  const int lane = threadIdx.x & 63;
  const int w    = threadIdx.x >> 6;
  const int quad = lane >> 4, c16 = lane & 15;
  const int wm = w >> 1, wn = w & 1;

  if (z == 2) {        // V^T: M=1024 feats (wv), N=4096 tokens (v f32)
    // flipped: tn (f32 token panels) XCD-exclusive, tm (wv) broadcast
    const int tm = (bx & 7) * 128, tn = (bx >> 3) * 128;
    gemm_core_128_bf32(wv, xvf, 1024, tm, tn, At, Bt, acc);
#pragma unroll
    for (int mi = 0; mi < 4; ++mi) {
#pragma unroll
      for (int ni = 0; ni < 4; ++ni) {
        const int n  = tn + wn * 64 + ni * 16 + c16;  // token
        const int bb = n >> 11, s = n & 2047;
#pragma unroll
        for (int r = 0; r < 4; ++r) {
          const int m  = tm + wm * 64 + mi * 16 + quad * 4 + r;  // feature
          const int hh = m >> 6, d = m & 63;
          Vo[(((size_t)(bb * 16 + hh) * 64 + d) << 11) + s] =
              (__bf16)(acc[mi][ni][r] + bv[m]);
        }
      }
    }
  } else {             // Q/K: M=4096 tokens (x f32), N=1024 feats (w)
    // tm (f32 token panels) XCD-exclusive, tn (weights) broadcast
    const int tm = (bx >> 3) * 128, tn = (bx & 7) * 128;
    const float*  A  = z ? xkf : xqf;
    const __bf16* BT = z ? wk : wq;
    const float*  bias = z ? bk : bq;
    gemm_core_128_af32(A, BT, 1024, tm, tn, At, Bt, acc);

    __bf16* Out = z ? Ko : Qo;
    const float scale = (z == 0) ? 0.1803368801f : 1.0f;  // 0.125 * log2(e)
#pragma unroll
    for (int mi = 0; mi < 4; ++mi) {
#pragma unroll
      for (int ni = 0; ni < 4; ++ni) {
        const int n  = tn + wn * 64 + ni * 16 + c16;  // feature
        const int hh = n >> 6, d = n & 63;
        const float bn = bias[n];
#pragma unroll
        for (int r = 0; r < 4; ++r) {
          const int m  = tm + wm * 64 + mi * 16 + quad * 4 + r;  // token
          const int bb = m >> 11, s = m & 2047;
          Out[(((size_t)(bb * 16 + hh) * 2048 + s) << 6) + d] =
              (__bf16)((acc[mi][ni][r] + bn) * scale);
        }
      }
    }
  }
}

// ---------------------------------------------------------------------------
// Output projection, 64x128 tile -> 512 blocks (2 blocks/CU).
// XCD-chunk swizzle (512 = 8 x 64): ctx panels XCD-exclusive.
// ---------------------------------------------------------------------------
__global__ __launch_bounds__(256)
void out_proj(const __bf16* __restrict__ ctx, const __bf16* __restrict__ wo,
              const float* __restrict__ bo, float* __restrict__ out) {
  __shared__ __bf16 At[64 * 32];
  __shared__ __bf16 Bt[128 * 32];
  const int bx0 = blockIdx.x;
  const int bx  = (bx0 & 7) * 64 + (bx0 >> 3);
  const int tm = (bx >> 3) * 64, tn = (bx & 7) * 128;

  const int tid  = threadIdx.x;
  const int lane = tid & 63, w = tid >> 6;
  const int quad = lane >> 4, c16 = lane & 15;
  const int wm = w >> 1, wn = w & 1;

  const int row0 = lane >> 2, col0 = (lane & 3) * 8;
  const __bf16* Ag = ctx + (size_t)(tm + w * 16 + row0) * 1024 + col0;
  const __bf16* Bg = wo  + (size_t)(tn + w * 32 + row0) * 1024 + col0;
  __bf16* Al = At + w * 512;
  __bf16* Bl = Bt + w * 1024;

  f32x4 acc[2][4];
  const f32x4 zero4 = {0.f, 0.f, 0.f, 0.f};
#pragma unroll
  for (int i = 0; i < 2; ++i)
#pragma unroll
    for (int j = 0; j < 4; ++j) acc[i][j] = zero4;

  for (int kt = 0; kt < 1024; kt += 32) {
    async_ld16(Ag + kt, Al);
    async_ld16(Bg + kt, Bl);
    async_ld16(Bg + 16 * 1024 + kt, Bl + 512);
    __syncthreads();

    bf16_8 af[2], bfr[4];
#pragma unroll
    for (int mi = 0; mi < 2; ++mi)
      af[mi] = *(const bf16_8*)(At + (wm * 32 + mi * 16 + c16) * 32 + quad * 8);
#pragma unroll
    for (int ni = 0; ni < 4; ++ni)
      bfr[ni] = *(const bf16_8*)(Bt + (wn * 64 + ni * 16 + c16) * 32 + quad * 8);
#pragma unroll
    for (int mi = 0; mi < 2; ++mi)
#pragma unroll
      for (int ni = 0; ni < 4; ++ni)
        acc[mi][ni] = MFMA16(af[mi], bfr[ni], acc[mi][ni]);
    __syncthreads();
  }

#pragma unroll
  for (int mi = 0; mi < 2; ++mi) {
#pragma unroll
    for (int ni = 0; ni < 4; ++ni) {
      const int n = tn + wn * 64 + ni * 16 + c16;
      const float bn = bo[n];
#pragma unroll
      for (int r = 0; r < 4; ++r) {
        const int m = tm + wm * 32 + mi * 16 + quad * 4 + r;
        out[(size_t)m * 1024 + n] = acc[mi][ni][r] + bn;
      }
    }
  }
}

// ---------------------------------------------------------------------------
// Flash attention — BYTE-IDENTICAL to R11/R12 (KVBLK=128, seed/exp2, 52.7 us).
// ---------------------------------------------------------------------------
__global__ __launch_bounds__(512, 4)
void flash_attn(const __bf16* __restrict__ Qg, const __bf16* __restrict__ Kg,
                const __bf16* __restrict__ VTg, const int* __restrict__ maskg,
                __bf16* __restrict__ ctx) {
  __shared__ __align__(16) char smem_[73216];

  const int t    = threadIdx.x;
  const int lane = t & 63;
  const int w    = t >> 6;
  const int g    = w & 3;    // q-group (32 rows)
  const int hh   = w >> 2;   // kv half
  const int n32  = lane & 31;
  const int h    = lane >> 5;

  // XCD swizzle: 512 blocks = 8 XCDs x 64; chunk so one XCD sees 4 heads' KV.
  const int linear = blockIdx.x + (blockIdx.y << 4) + (blockIdx.z << 8);
  const int sw     = (linear & 7) * 64 + (linear >> 3);
  const int qt     = sw & 15;
  const int head   = (sw >> 4) & 15;
  const int b      = sw >> 8;

  const size_t bh = (size_t)(b * 16 + head);
  const int qbase = qt * 128 + g * 32;

  // Q b-frags (B-operand: lane&31 = q row, k-chunk by lane>>5). Pre-scaled
  // by 0.125*log2e, so QK^T lands directly in the log2 domain.
  bf16_8 bq[4];
  {
    const __bf16* qptr = Qg + (bh * 2048 + qbase + n32) * 64 + h * 8;
#pragma unroll
    for (int s = 0; s < 4; ++s) bq[s] = *(const bf16_8*)(qptr + s * 16);
  }

  const f32x16 z16 = {0.f,0.f,0.f,0.f,0.f,0.f,0.f,0.f,
                      0.f,0.f,0.f,0.f,0.f,0.f,0.f,0.f};
  f32x16 o0 = z16, o1 = z16;   // O[32q x 64d]: dt=0,1
  float lsum = 0.f;

  // per-half LDS views (addresses loop-invariant)
  __bf16* const Kl = (__bf16*)smem_           + hh * (128 * 72);
  __bf16* const Vl = (__bf16*)(smem_ + 36864) + hh * (64 * 136);
  float*  const Ml = (float*)(smem_ + 71680)  + hh * 128;

  // staging: threads 0-255 stage half 0, 256-511 half 1 (hh == t>>8)
  const int tl   = t & 255;
  const int srow = tl >> 2, scc = (tl & 3) * 16;
  const __bf16* Kgp = Kg  + (bh * 2048 + hh * 1024) * 64;
  const __bf16* Vgp = VTg + bh * 64 * 2048 + hh * 1024;
  const int*    mgp = maskg + b * 2048 + hh * 1024;

  for (int ktb = 0; ktb < 1024; ktb += 128) {
    // stage 128 keys: K rows [ktb, ktb+128) and V^T cols [ktb, ktb+128)
#pragma unroll
    for (int r2 = 0; r2 < 2; ++r2) {
      const size_t kb = (size_t)(ktb + r2 * 64 + srow) * 64 + scc;
      __bf16* kw = Kl + (r2 * 64 + srow) * 72 + scc;
      *(bf16_8*)kw       = *(const bf16_8*)&Kgp[kb];
      *(bf16_8*)(kw + 8) = *(const bf16_8*)&Kgp[kb + 8];
      const size_t vb = (size_t)srow * 2048 + ktb + r2 * 64 + scc;
      __bf16* vw = Vl + srow * 136 + r2 * 64 + scc;
      *(bf16_8*)vw       = *(const bf16_8*)&Vgp[vb];
      *(bf16_8*)(vw + 8) = *(const bf16_8*)&Vgp[vb + 8];
    }
    if (tl < 128) Ml[tl] = mgp[ktb + tl] ? -17.3123404907f : -1e30f;
    __syncthreads();

#pragma unroll
    for (int kt2 = 0; kt2 < 4; ++kt2) {
      // S^T = K · Q^T, accumulator SEEDED with the log2-domain mask additive:
      // p[4j+e] needs maskadd[kt2*32 + e + 8j + 4h]
      f32x16 p;
#pragma unroll
      for (int j = 0; j < 4; ++j) {
        const f32x4 m4 = *(const f32x4*)&Ml[kt2 * 32 + 8 * j + 4 * h];
        p[4 * j + 0] = m4[0];
        p[4 * j + 1] = m4[1];
        p[4 * j + 2] = m4[2];
        p[4 * j + 3] = m4[3];
      }
#pragma unroll
      for (int s = 0; s < 4; ++s) {
        const bf16_8 ka =
            *(const bf16_8*)&Kl[(kt2 * 32 + n32) * 72 + s * 16 + h * 8];
        p = MFMA32(ka, bq[s], p);
      }

      // softmax: bare exp2 (Q carried log2e; mask & -12 shift already in p)
      unsigned c[8];
#pragma unroll
      for (int i = 0; i < 8; ++i) {
        const float e0 = __builtin_amdgcn_exp2f(p[2 * i]);
        const float e1 = __builtin_amdgcn_exp2f(p[2 * i + 1]);
        lsum += e0 + e1;
        union { __bf16 hx[2]; unsigned u; } uu;
        uu.hx[0] = (__bf16)e0;
        uu.hx[1] = (__bf16)e1;
        c[i] = uu.u;
      }
      // redistribute to PV A-frag layout
      asm volatile("v_permlane32_swap_b32 %0, %1" : "+v"(c[0]), "+v"(c[2]));
      asm volatile("v_permlane32_swap_b32 %0, %1" : "+v"(c[1]), "+v"(c[3]));
      asm volatile("v_permlane32_swap_b32 %0, %1" : "+v"(c[4]), "+v"(c[6]));
      asm volatile("v_permlane32_swap_b32 %0, %1" : "+v"(c[5]), "+v"(c[7]));

#pragma unroll
      for (int sub = 0; sub < 2; ++sub) {
        const u32x4 av = {c[4 * sub + 0], c[4 * sub + 1],
                          c[4 * sub + 2], c[4 * sub + 3]};
        const bf16_8 aP = __builtin_bit_cast(bf16_8, av);
        const int s = kt2 * 2 + sub;   // k-slot within the 128-key tile
        const bf16_8 vb0 =
            *(const bf16_8*)&Vl[n32 * 136 + s * 16 + h * 8];
        const bf16_8 vb1 =
            *(const bf16_8*)&Vl[(32 + n32) * 136 + s * 16 + h * 8];
        o0 = MFMA32(aP, vb0, o0);
        o1 = MFMA32(aP, vb1, o1);
      }
    }
    __syncthreads();
  }

  // full row-sum over this wave's kv-half (lane's two k subsets are disjoint)
  lsum += __shfl_xor(lsum, 32);

  float (*Om)[32][64] = (float(*)[32][64])smem_;          // overlays staging
  float (*Lm)[32]     = (float(*)[32])(smem_ + 72704);

  if (hh) {  // upper half: publish partials
#pragma unroll
    for (int r = 0; r < 16; ++r) {
      const int qrow = (r & 3) + 8 * (r >> 2) + 4 * h;
      Om[g][qrow][n32]      = o0[r];
      Om[g][qrow][32 + n32] = o1[r];
    }
    if (h == 0) Lm[g][n32] = lsum;
  }
  __syncthreads();
  if (!hh) {  // lower half: merge, normalize, store
    const float linv = 1.0f / (lsum + Lm[g][n32]);
#pragma unroll
    for (int r = 0; r < 16; ++r) {
      const int qrow = (r & 3) + 8 * (r >> 2) + 4 * h;
      const float li = __shfl(linv, qrow);
      __bf16* cp = ctx + ((size_t)b * 2048 + qbase + qrow) * 1024 + head * 64;
      cp[n32]      = (__bf16)((o0[r] + Om[g][qrow][n32]) * li);
      cp[32 + n32] = (__bf16)((o1[r] + Om[g][qrow][32 + n32]) * li);
    }
  }
}

// ---------------------------------------------------------------------------
// weights-only f32 -> bf16 converter: 4 x [1024x1024]. grid (512,4)x256.
// ---------------------------------------------------------------------------
__global__ __launch_bounds__(256)
void cvt_w(const float* __restrict__ Wq, const float* __restrict__ Wk,
           const float* __restrict__ Wv, const float* __restrict__ Wo,
           __bf16* __restrict__ wqb, __bf16* __restrict__ wkb,
           __bf16* __restrict__ wvb, __bf16* __restrict__ wob) {
  const int y = blockIdx.y;
  const float* s;
  __bf16* d;
  switch (y) {
    case 0:  s = Wq; d = wqb; break;
    case 1:  s = Wk; d = wkb; break;
    case 2:  s = Wv; d = wvb; break;
    default: s = Wo; d = wob; break;
  }
  const int i = blockIdx.x * blockDim.x + threadIdx.x;
  const float4* sp = (const float4*)s;
  const float4 v0 = sp[i * 2], v1 = sp[i * 2 + 1];
  bf16_8 o;
  o[0] = (__bf16)v0.x; o[1] = (__bf16)v0.y;
  o[2] = (__bf16)v0.z; o[3] = (__bf16)v0.w;
  o[4] = (__bf16)v1.x; o[5] = (__bf16)v1.y;
  o[6] = (__bf16)v1.z; o[7] = (__bf16)v1.w;
  *(bf16_8*)(d + (size_t)i * 8) = o;
}

// ---------------------------------------------------------------------------
extern "C" void kernel_launch(void* const* d_in, const int* in_sizes, int n_in,
                              void* d_out, int out_size, void* d_ws, size_t ws_size,
                              hipStream_t stream) {
  (void)in_sizes; (void)n_in; (void)out_size; (void)ws_size;
  const float* q    = (const float*)d_in[0];
  const float* k    = (const float*)d_in[1];
  const float* v    = (const float*)d_in[2];
  const int*   mask = (const int*)d_in[3];
  const float* Wq = (const float*)d_in[4];
  const float* bq = (const float*)d_in[5];
  const float* Wk = (const float*)d_in[6];
  const float* bk = (const float*)d_in[7];
  const float* Wv = (const float*)d_in[8];
  const float* bv = (const float*)d_in[9];
  const float* Wo = (const float*)d_in[10];
  const float* bo = (const float*)d_in[11];

  char* ws = (char*)d_ws;
  const size_t MB = 1ull << 20;
  __bf16* wqb = (__bf16*)(ws + 24 * MB);
  __bf16* wkb = (__bf16*)(ws + 26 * MB);
  __bf16* wvb = (__bf16*)(ws + 28 * MB);
  __bf16* wob = (__bf16*)(ws + 30 * MB);
  __bf16* Qb  = (__bf16*)(ws + 32 * MB);
  __bf16* Kb  = (__bf16*)(ws + 40 * MB);
  __bf16* VTb = (__bf16*)(ws + 48 * MB);
  __bf16* ctx = (__bf16*)(ws + 56 * MB);

  cvt_w<<<dim3(512, 4), 256, 0, stream>>>(Wq, Wk, Wv, Wo,
                                          wqb, wkb, wvb, wob);

  qkv_fused<<<dim3(256, 1, 3), 256, 0, stream>>>(q, k, v, wqb, wkb, wvb,
                                                 bq, bk, bv, Qb, Kb, VTb);

  flash_attn<<<dim3(16, 16, 2), 512, 0, stream>>>(Qb, Kb, VTb, mask, ctx);

  out_proj<<<dim3(512), 256, 0, stream>>>(ctx, wob, bo, (float*)d_out);
}

// Round 10
// 222.263 us; speedup vs baseline: 1.0543x; 1.0002x over previous
//
#include <hip/hip_runtime.h>

// ---------------------------------------------------------------------------
// MultiHeadAttention (B=2, S=2048, D=1024, H=16, dk=64) on gfx950
// R14 = R13 with T4 counted-vmcnt pipelining in the qkv f32-staged cores:
//  - f32 operand register-PREFETCH (tile kt+32 issued before the MFMA burst)
//  - mid barrier: s_waitcnt vmcnt(4) lgkmcnt(0) + raw s_barrier -> drains the
//    2 async-B loads + ds_writes but keeps the 4 prefetched f32 loads IN
//    FLIGHT across the barrier (the __syncthreads vmcnt(0) drain was the tax)
//  - trailing barrier: raw s_barrier (reads are register-consumed pre-arrival)
//  - issue-order fences pin async-B before f32-prefetch (vmcnt count depends)
//  - last iteration peels to vmcnt(0)
// flash_attn / out_proj / cvt_w BYTE-IDENTICAL to R13.
// ---------------------------------------------------------------------------

typedef __bf16 bf16_8 __attribute__((ext_vector_type(8)));
typedef float  f32x4  __attribute__((ext_vector_type(4)));
typedef float  f32x16 __attribute__((ext_vector_type(16)));
typedef unsigned int u32x4 __attribute__((ext_vector_type(4)));

#define MFMA16(a, b, c) __builtin_amdgcn_mfma_f32_16x16x32_bf16((a), (b), (c), 0, 0, 0)
#define MFMA32(a, b, c) __builtin_amdgcn_mfma_f32_32x32x16_bf16((a), (b), (c), 0, 0, 0)

__device__ __forceinline__ void async_ld16(const void* g, void* l) {
  __builtin_amdgcn_global_load_lds(
      (__attribute__((address_space(1))) void*)g,
      (__attribute__((address_space(3))) void*)l, 16, 0, 0);
}

// ---------------------------------------------------------------------------
// Variant A-f32 + prefetch/counted-vmcnt: A [MxK] f32 reg-staged+converted,
// BT [NxK] bf16 via global_load_lds.
// ---------------------------------------------------------------------------
__device__ __forceinline__ void gemm_core_128_af32(
    const float* __restrict__ A, const __bf16* __restrict__ BT, int K,
    int tm, int tn, __bf16* At, __bf16* Bt, f32x4 acc[4][4]) {
  const int tid  = threadIdx.x;
  const int lane = tid & 63;
  const int w    = tid >> 6;
  const int quad = lane >> 4;
  const int c16  = lane & 15;
  const int wm = w >> 1, wn = w & 1;

  const int ch0  = w * 2;
  const int row0 = ch0 * 16 + (lane >> 2);
  const int col0 = (lane & 3) * 8;
  const float*  Ag = A  + (size_t)(tm + row0) * K + col0;
  const __bf16* Bg = BT + (size_t)(tn + row0) * K + col0;
  __bf16* Aw = At + ch0 * 512 + lane * 8;
  __bf16* Bl = Bt + ch0 * 512;
  const size_t rowK16 = (size_t)16 * K;

  // prologue: prefetch f32 tile kt=0
  f32x4 a00 = *(const f32x4*)(Ag);
  f32x4 a01 = *(const f32x4*)(Ag + 4);
  f32x4 a10 = *(const f32x4*)(Ag + rowK16);
  f32x4 a11 = *(const f32x4*)(Ag + rowK16 + 4);

  for (int kt = 0; kt < K; kt += 32) {
    // cvt prefetched regs (compiler-inserted vmcnt wait lands HERE — the
    // loads had a full iteration to complete) and write the A tile.
    bf16_8 c0, c1;
#pragma unroll
    for (int i2 = 0; i2 < 4; ++i2) {
      c0[i2]     = (__bf16)a00[i2];
      c0[4 + i2] = (__bf16)a01[i2];
      c1[i2]     = (__bf16)a10[i2];
      c1[4 + i2] = (__bf16)a11[i2];
    }
    *(bf16_8*)Aw         = c0;
    *(bf16_8*)(Aw + 512) = c1;

    // async-B for current step: vm ops issued FIRST (oldest)
    async_ld16(Bg + kt,          Bl);
    async_ld16(Bg + rowK16 + kt, Bl + 512);
    asm volatile("" ::: "memory");   // pin issue order: async-B before prefetch

    if (kt + 32 < K) {
      // prefetch f32 tile kt+32 (vm ops 3..6, newest)
      a00 = *(const f32x4*)(Ag + kt + 32);
      a01 = *(const f32x4*)(Ag + kt + 36);
      a10 = *(const f32x4*)(Ag + rowK16 + kt + 32);
      a11 = *(const f32x4*)(Ag + rowK16 + kt + 36);
      // drain async-B (2 oldest) + ds_writes; keep 4 f32 loads in flight
      asm volatile("s_waitcnt vmcnt(4) lgkmcnt(0)" ::: "memory");
    } else {
      asm volatile("s_waitcnt vmcnt(0) lgkmcnt(0)" ::: "memory");
    }
    __builtin_amdgcn_s_barrier();

    bf16_8 af[4], bfr[4];
#pragma unroll
    for (int mi = 0; mi < 4; ++mi)
      af[mi] = *(const bf16_8*)(At + (wm * 64 + mi * 16 + c16) * 32 + quad * 8);
#pragma unroll
    for (int ni = 0; ni < 4; ++ni)
      bfr[ni] = *(const bf16_8*)(Bt + (wn * 64 + ni * 16 + c16) * 32 + quad * 8);
#pragma unroll
    for (int mi = 0; mi < 4; ++mi)
#pragma unroll
      for (int ni = 0; ni < 4; ++ni)
        acc[mi][ni] = MFMA16(af[mi], bfr[ni], acc[mi][ni]);

    // trailing barrier: raw — each wave's ds_reads were register-consumed
    // (auto lgkmcnt before MFMA) before it arrives; no drain required.
    __builtin_amdgcn_s_barrier();
  }
}

// ---------------------------------------------------------------------------
// Variant B-f32 + prefetch/counted-vmcnt: A bf16 via global_load_lds,
// BT f32 reg-staged+converted.
// ---------------------------------------------------------------------------
__device__ __forceinline__ void gemm_core_128_bf32(
    const __bf16* __restrict__ A, const float* __restrict__ BT, int K,
    int tm, int tn, __bf16* At, __bf16* Bt, f32x4 acc[4][4]) {
  const int tid  = threadIdx.x;
  const int lane = tid & 63;
  const int w    = tid >> 6;
  const int quad = lane >> 4;
  const int c16  = lane & 15;
  const int wm = w >> 1, wn = w & 1;

  const int ch0  = w * 2;
  const int row0 = ch0 * 16 + (lane >> 2);
  const int col0 = (lane & 3) * 8;
  const __bf16* Ag = A  + (size_t)(tm + row0) * K + col0;
  const float*  Bg = BT + (size_t)(tn + row0) * K + col0;
  __bf16* Al = At + ch0 * 512;
  __bf16* Bw = Bt + ch0 * 512 + lane * 8;
  const size_t rowK16 = (size_t)16 * K;

  f32x4 b00 = *(const f32x4*)(Bg);
  f32x4 b01 = *(const f32x4*)(Bg + 4);
  f32x4 b10 = *(const f32x4*)(Bg + rowK16);
  f32x4 b11 = *(const f32x4*)(Bg + rowK16 + 4);

  for (int kt = 0; kt < K; kt += 32) {
    bf16_8 c0, c1;
#pragma unroll
    for (int i2 = 0; i2 < 4; ++i2) {
      c0[i2]     = (__bf16)b00[i2];
      c0[4 + i2] = (__bf16)b01[i2];
      c1[i2]     = (__bf16)b10[i2];
      c1[4 + i2] = (__bf16)b11[i2];
    }
    *(bf16_8*)Bw         = c0;
    *(bf16_8*)(Bw + 512) = c1;

    async_ld16(Ag + kt,          Al);
    async_ld16(Ag + rowK16 + kt, Al + 512);
    asm volatile("" ::: "memory");

    if (kt + 32 < K) {
      b00 = *(const f32x4*)(Bg + kt + 32);
      b01 = *(const f32x4*)(Bg + kt + 36);
      b10 = *(const f32x4*)(Bg + rowK16 + kt + 32);
      b11 = *(const f32x4*)(Bg + rowK16 + kt + 36);
      asm volatile("s_waitcnt vmcnt(4) lgkmcnt(0)" ::: "memory");
    } else {
      asm volatile("s_waitcnt vmcnt(0) lgkmcnt(0)" ::: "memory");
    }
    __builtin_amdgcn_s_barrier();

    bf16_8 af[4], bfr[4];
#pragma unroll
    for (int mi = 0; mi < 4; ++mi)
      af[mi] = *(const bf16_8*)(At + (wm * 64 + mi * 16 + c16) * 32 + quad * 8);
#pragma unroll
    for (int ni = 0; ni < 4; ++ni)
      bfr[ni] = *(const bf16_8*)(Bt + (wn * 64 + ni * 16 + c16) * 32 + quad * 8);
#pragma unroll
    for (int mi = 0; mi < 4; ++mi)
#pragma unroll
      for (int ni = 0; ni < 4; ++ni)
        acc[mi][ni] = MFMA16(af[mi], bfr[ni], acc[mi][ni]);

    __builtin_amdgcn_s_barrier();
  }
}

// ---------------------------------------------------------------------------
// Fused QKV projection, f32 activations in. grid = (256,1,3).
// V produced transposed [B,H,64,S]. Q pre-scaled by 0.125*log2e.
// XCD-chunk swizzle: the 8 blocks sharing an f32 panel co-reside on one XCD.
// ---------------------------------------------------------------------------
__global__ __launch_bounds__(256)
void qkv_fused(const float* __restrict__ xqf, const float* __restrict__ xkf,
               const float* __restrict__ xvf,
               const __bf16* __restrict__ wq, const __bf16* __restrict__ wk,
               const __bf16* __restrict__ wv,
               const float* __restrict__ bq, const float* __restrict__ bk,
               const float* __restrict__ bv,
               __bf16* __restrict__ Qo, __bf16* __restrict__ Ko,
               __bf16* __restrict__ Vo) {
  __shared__ __bf16 At[128 * 32];
  __shared__ __bf16 Bt[128 * 32];
  const int z   = blockIdx.z;
  const int bx0 = blockIdx.x;
  const int bx  = (bx0 & 7) * 32 + (bx0 >> 3);   // XCD chunk

  f32x4 acc[4][4];
  const f32x4 zero4 = {0.f, 0.f, 0.f, 0.f};
#pragma unroll
  for (int i = 0; i < 4; ++i)
#pragma unroll
    for (int j = 0; j < 4; ++j) acc[i][j] = zero4;

  const int lane = threadIdx.x & 63;
  const int w    = threadIdx.x >> 6;
  const int quad = lane >> 4, c16 = lane & 15;
  const int wm = w >> 1, wn = w & 1;

  if (z == 2) {        // V^T: M=1024 feats (wv), N=4096 tokens (v f32)
    const int tm = (bx & 7) * 128, tn = (bx >> 3) * 128;
    gemm_core_128_bf32(wv, xvf, 1024, tm, tn, At, Bt, acc);
#pragma unroll
    for (int mi = 0; mi < 4; ++mi) {
#pragma unroll
      for (int ni = 0; ni < 4; ++ni) {
        const int n  = tn + wn * 64 + ni * 16 + c16;  // token
        const int bb = n >> 11, s = n & 2047;
#pragma unroll
        for (int r = 0; r < 4; ++r) {
          const int m  = tm + wm * 64 + mi * 16 + quad * 4 + r;  // feature
          const int hh = m >> 6, d = m & 63;
          Vo[(((size_t)(bb * 16 + hh) * 64 + d) << 11) + s] =
              (__bf16)(acc[mi][ni][r] + bv[m]);
        }
      }
    }
  } else {             // Q/K: M=4096 tokens (x f32), N=1024 feats (w)
    const int tm = (bx >> 3) * 128, tn = (bx & 7) * 128;
    const float*  A  = z ? xkf : xqf;
    const __bf16* BT = z ? wk : wq;
    const float*  bias = z ? bk : bq;
    gemm_core_128_af32(A, BT, 1024, tm, tn, At, Bt, acc);

    __bf16* Out = z ? Ko : Qo;
    const float scale = (z == 0) ? 0.1803368801f : 1.0f;  // 0.125 * log2(e)
#pragma unroll
    for (int mi = 0; mi < 4; ++mi) {
#pragma unroll
      for (int ni = 0; ni < 4; ++ni) {
        const int n  = tn + wn * 64 + ni * 16 + c16;  // feature
        const int hh = n >> 6, d = n & 63;
        const float bn = bias[n];
#pragma unroll
        for (int r = 0; r < 4; ++r) {
          const int m  = tm + wm * 64 + mi * 16 + quad * 4 + r;  // token
          const int bb = m >> 11, s = m & 2047;
          Out[(((size_t)(bb * 16 + hh) * 2048 + s) << 6) + d] =
              (__bf16)((acc[mi][ni][r] + bn) * scale);
        }
      }
    }
  }
}

// ---------------------------------------------------------------------------
// Output projection, 64x128 tile -> 512 blocks (2 blocks/CU).
// XCD-chunk swizzle (512 = 8 x 64): ctx panels XCD-exclusive.
// ---------------------------------------------------------------------------
__global__ __launch_bounds__(256)
void out_proj(const __bf16* __restrict__ ctx, const __bf16* __restrict__ wo,
              const float* __restrict__ bo, float* __restrict__ out) {
  __shared__ __bf16 At[64 * 32];
  __shared__ __bf16 Bt[128 * 32];
  const int bx0 = blockIdx.x;
  const int bx  = (bx0 & 7) * 64 + (bx0 >> 3);
  const int tm = (bx >> 3) * 64, tn = (bx & 7) * 128;

  const int tid  = threadIdx.x;
  const int lane = tid & 63, w = tid >> 6;
  const int quad = lane >> 4, c16 = lane & 15;
  const int wm = w >> 1, wn = w & 1;

  const int row0 = lane >> 2, col0 = (lane & 3) * 8;
  const __bf16* Ag = ctx + (size_t)(tm + w * 16 + row0) * 1024 + col0;
  const __bf16* Bg = wo  + (size_t)(tn + w * 32 + row0) * 1024 + col0;
  __bf16* Al = At + w * 512;
  __bf16* Bl = Bt + w * 1024;

  f32x4 acc[2][4];
  const f32x4 zero4 = {0.f, 0.f, 0.f, 0.f};
#pragma unroll
  for (int i = 0; i < 2; ++i)
#pragma unroll
    for (int j = 0; j < 4; ++j) acc[i][j] = zero4;

  for (int kt = 0; kt < 1024; kt += 32) {
    async_ld16(Ag + kt, Al);
    async_ld16(Bg + kt, Bl);
    async_ld16(Bg + 16 * 1024 + kt, Bl + 512);
    __syncthreads();

    bf16_8 af[2], bfr[4];
#pragma unroll
    for (int mi = 0; mi < 2; ++mi)
      af[mi] = *(const bf16_8*)(At + (wm * 32 + mi * 16 + c16) * 32 + quad * 8);
#pragma unroll
    for (int ni = 0; ni < 4; ++ni)
      bfr[ni] = *(const bf16_8*)(Bt + (wn * 64 + ni * 16 + c16) * 32 + quad * 8);
#pragma unroll
    for (int mi = 0; mi < 2; ++mi)
#pragma unroll
      for (int ni = 0; ni < 4; ++ni)
        acc[mi][ni] = MFMA16(af[mi], bfr[ni], acc[mi][ni]);
    __syncthreads();
  }

#pragma unroll
  for (int mi = 0; mi < 2; ++mi) {
#pragma unroll
    for (int ni = 0; ni < 4; ++ni) {
      const int n = tn + wn * 64 + ni * 16 + c16;
      const float bn = bo[n];
#pragma unroll
      for (int r = 0; r < 4; ++r) {
        const int m = tm + wm * 32 + mi * 16 + quad * 4 + r;
        out[(size_t)m * 1024 + n] = acc[mi][ni][r] + bn;
      }
    }
  }
}

// ---------------------------------------------------------------------------
// Flash attention — BYTE-IDENTICAL to R11/R12/R13 (KVBLK=128, seed/exp2).
// ---------------------------------------------------------------------------
__global__ __launch_bounds__(512, 4)
void flash_attn(const __bf16* __restrict__ Qg, const __bf16* __restrict__ Kg,
                const __bf16* __restrict__ VTg, const int* __restrict__ maskg,
                __bf16* __restrict__ ctx) {
  __shared__ __align__(16) char smem_[73216];

  const int t    = threadIdx.x;
  const int lane = t & 63;
  const int w    = t >> 6;
  const int g    = w & 3;    // q-group (32 rows)
  const int hh   = w >> 2;   // kv half
  const int n32  = lane & 31;
  const int h    = lane >> 5;

  // XCD swizzle: 512 blocks = 8 XCDs x 64; chunk so one XCD sees 4 heads' KV.
  const int linear = blockIdx.x + (blockIdx.y << 4) + (blockIdx.z << 8);
  const int sw     = (linear & 7) * 64 + (linear >> 3);
  const int qt     = sw & 15;
  const int head   = (sw >> 4) & 15;
  const int b      = sw >> 8;

  const size_t bh = (size_t)(b * 16 + head);
  const int qbase = qt * 128 + g * 32;

  // Q b-frags (B-operand: lane&31 = q row, k-chunk by lane>>5). Pre-scaled
  // by 0.125*log2e, so QK^T lands directly in the log2 domain.
  bf16_8 bq[4];
  {
    const __bf16* qptr = Qg + (bh * 2048 + qbase + n32) * 64 + h * 8;
#pragma unroll
    for (int s = 0; s < 4; ++s) bq[s] = *(const bf16_8*)(qptr + s * 16);
  }

  const f32x16 z16 = {0.f,0.f,0.f,0.f,0.f,0.f,0.f,0.f,
                      0.f,0.f,0.f,0.f,0.f,0.f,0.f,0.f};
  f32x16 o0 = z16, o1 = z16;   // O[32q x 64d]: dt=0,1
  float lsum = 0.f;

  // per-half LDS views (addresses loop-invariant)
  __bf16* const Kl = (__bf16*)smem_           + hh * (128 * 72);
  __bf16* const Vl = (__bf16*)(smem_ + 36864) + hh * (64 * 136);
  float*  const Ml = (float*)(smem_ + 71680)  + hh * 128;

  // staging: threads 0-255 stage half 0, 256-511 half 1 (hh == t>>8)
  const int tl   = t & 255;
  const int srow = tl >> 2, scc = (tl & 3) * 16;
  const __bf16* Kgp = Kg  + (bh * 2048 + hh * 1024) * 64;
  const __bf16* Vgp = VTg + bh * 64 * 2048 + hh * 1024;
  const int*    mgp = maskg + b * 2048 + hh * 1024;

  for (int ktb = 0; ktb < 1024; ktb += 128) {
    // stage 128 keys: K rows [ktb, ktb+128) and V^T cols [ktb, ktb+128)
#pragma unroll
    for (int r2 = 0; r2 < 2; ++r2) {
      const size_t kb = (size_t)(ktb + r2 * 64 + srow) * 64 + scc;
      __bf16* kw = Kl + (r2 * 64 + srow) * 72 + scc;
      *(bf16_8*)kw       = *(const bf16_8*)&Kgp[kb];
      *(bf16_8*)(kw + 8) = *(const bf16_8*)&Kgp[kb + 8];
      const size_t vb = (size_t)srow * 2048 + ktb + r2 * 64 + scc;
      __bf16* vw = Vl + srow * 136 + r2 * 64 + scc;
      *(bf16_8*)vw       = *(const bf16_8*)&Vgp[vb];
      *(bf16_8*)(vw + 8) = *(const bf16_8*)&Vgp[vb + 8];
    }
    if (tl < 128) Ml[tl] = mgp[ktb + tl] ? -17.3123404907f : -1e30f;
    __syncthreads();

#pragma unroll
    for (int kt2 = 0; kt2 < 4; ++kt2) {
      // S^T = K · Q^T, accumulator SEEDED with the log2-domain mask additive:
      // p[4j+e] needs maskadd[kt2*32 + e + 8j + 4h]
      f32x16 p;
#pragma unroll
      for (int j = 0; j < 4; ++j) {
        const f32x4 m4 = *(const f32x4*)&Ml[kt2 * 32 + 8 * j + 4 * h];
        p[4 * j + 0] = m4[0];
        p[4 * j + 1] = m4[1];
        p[4 * j + 2] = m4[2];
        p[4 * j + 3] = m4[3];
      }
#pragma unroll
      for (int s = 0; s < 4; ++s) {
        const bf16_8 ka =
            *(const bf16_8*)&Kl[(kt2 * 32 + n32) * 72 + s * 16 + h * 8];
        p = MFMA32(ka, bq[s], p);
      }

      // softmax: bare exp2 (Q carried log2e; mask & -12 shift already in p)
      unsigned c[8];
#pragma unroll
      for (int i = 0; i < 8; ++i) {
        const float e0 = __builtin_amdgcn_exp2f(p[2 * i]);
        const float e1 = __builtin_amdgcn_exp2f(p[2 * i + 1]);
        lsum += e0 + e1;
        union { __bf16 hx[2]; unsigned u; } uu;
        uu.hx[0] = (__bf16)e0;
        uu.hx[1] = (__bf16)e1;
        c[i] = uu.u;
      }
      // redistribute to PV A-frag layout
      asm volatile("v_permlane32_swap_b32 %0, %1" : "+v"(c[0]), "+v"(c[2]));
      asm volatile("v_permlane32_swap_b32 %0, %1" : "+v"(c[1]), "+v"(c[3]));
      asm volatile("v_permlane32_swap_b32 %0, %1" : "+v"(c[4]), "+v"(c[6]));
      asm volatile("v_permlane32_swap_b32 %0, %1" : "+v"(c[5]), "+v"(c[7]));

#pragma unroll
      for (int sub = 0; sub < 2; ++sub) {
        const u32x4 av = {c[4 * sub + 0], c[4 * sub + 1],
                          c[4 * sub + 2], c[4 * sub + 3]};
        const bf16_8 aP = __builtin_bit_cast(bf16_8, av);
        const int s = kt2 * 2 + sub;   // k-slot within the 128-key tile
        const bf16_8 vb0 =
            *(const bf16_8*)&Vl[n32 * 136 + s * 16 + h * 8];
        const bf16_8 vb1 =
            *(const bf16_8*)&Vl[(32 + n32) * 136 + s * 16 + h * 8];
        o0 = MFMA32(aP, vb0, o0);
        o1 = MFMA32(aP, vb1, o1);
      }
    }
    __syncthreads();
  }

  // full row-sum over this wave's kv-half (lane's two k subsets are disjoint)
  lsum += __shfl_xor(lsum, 32);

  float (*Om)[32][64] = (float(*)[32][64])smem_;          // overlays staging
  float (*Lm)[32]     = (float(*)[32])(smem_ + 72704);

  if (hh) {  // upper half: publish partials
#pragma unroll
    for (int r = 0; r < 16; ++r) {
      const int qrow = (r & 3) + 8 * (r >> 2) + 4 * h;
      Om[g][qrow][n32]      = o0[r];
      Om[g][qrow][32 + n32] = o1[r];
    }
    if (h == 0) Lm[g][n32] = lsum;
  }
  __syncthreads();
  if (!hh) {  // lower half: merge, normalize, store
    const float linv = 1.0f / (lsum + Lm[g][n32]);
#pragma unroll
    for (int r = 0; r < 16; ++r) {
      const int qrow = (r & 3) + 8 * (r >> 2) + 4 * h;
      const float li = __shfl(linv, qrow);
      __bf16* cp = ctx + ((size_t)b * 2048 + qbase + qrow) * 1024 + head * 64;
      cp[n32]      = (__bf16)((o0[r] + Om[g][qrow][n32]) * li);
      cp[32 + n32] = (__bf16)((o1[r] + Om[g][qrow][32 + n32]) * li);
    }
  }
}

// ---------------------------------------------------------------------------
// weights-only f32 -> bf16 converter: 4 x [1024x1024]. grid (512,4)x256.
// ---------------------------------------------------------------------------
__global__ __launch_bounds__(256)
void cvt_w(const float* __restrict__ Wq, const float* __restrict__ Wk,
           const float* __restrict__ Wv, const float* __restrict__ Wo,
           __bf16* __restrict__ wqb, __bf16* __restrict__ wkb,
           __bf16* __restrict__ wvb, __bf16* __restrict__ wob) {
  const int y = blockIdx.y;
  const float* s;
  __bf16* d;
  switch (y) {
    case 0:  s = Wq; d = wqb; break;
    case 1:  s = Wk; d = wkb; break;
    case 2:  s = Wv; d = wvb; break;
    default: s = Wo; d = wob; break;
  }
  const int i = blockIdx.x * blockDim.x + threadIdx.x;
  const float4* sp = (const float4*)s;
  const float4 v0 = sp[i * 2], v1 = sp[i * 2 + 1];
  bf16_8 o;
  o[0] = (__bf16)v0.x; o[1] = (__bf16)v0.y;
  o[2] = (__bf16)v0.z; o[3] = (__bf16)v0.w;
  o[4] = (__bf16)v1.x; o[5] = (__bf16)v1.y;
  o[6] = (__bf16)v1.z; o[7] = (__bf16)v1.w;
  *(bf16_8*)(d + (size_t)i * 8) = o;
}

// ---------------------------------------------------------------------------
extern "C" void kernel_launch(void* const* d_in, const int* in_sizes, int n_in,
                              void* d_out, int out_size, void* d_ws, size_t ws_size,
                              hipStream_t stream) {
  (void)in_sizes; (void)n_in; (void)out_size; (void)ws_size;
  const float* q    = (const float*)d_in[0];
  const float* k    = (const float*)d_in[1];
  const float* v    = (const float*)d_in[2];
  const int*   mask = (const int*)d_in[3];
  const float* Wq = (const float*)d_in[4];
  const float* bq = (const float*)d_in[5];
  const float* Wk = (const float*)d_in[6];
  const float* bk = (const float*)d_in[7];
  const float* Wv = (const float*)d_in[8];
  const float* bv = (const float*)d_in[9];
  const float* Wo = (const float*)d_in[10];
  const float* bo = (const float*)d_in[11];

  char* ws = (char*)d_ws;
  const size_t MB = 1ull << 20;
  __bf16* wqb = (__bf16*)(ws + 24 * MB);
  __bf16* wkb = (__bf16*)(ws + 26 * MB);
  __bf16* wvb = (__bf16*)(ws + 28 * MB);
  __bf16* wob = (__bf16*)(ws + 30 * MB);
  __bf16* Qb  = (__bf16*)(ws + 32 * MB);
  __bf16* Kb  = (__bf16*)(ws + 40 * MB);
  __bf16* VTb = (__bf16*)(ws + 48 * MB);
  __bf16* ctx = (__bf16*)(ws + 56 * MB);

  cvt_w<<<dim3(512, 4), 256, 0, stream>>>(Wq, Wk, Wv, Wo,
                                          wqb, wkb, wvb, wob);

  qkv_fused<<<dim3(256, 1, 3), 256, 0, stream>>>(q, k, v, wqb, wkb, wvb,
                                                 bq, bk, bv, Qb, Kb, VTb);

  flash_attn<<<dim3(16, 16, 2), 512, 0, stream>>>(Qb, Kb, VTb, mask, ctx);

  out_proj<<<dim3(512), 256, 0, stream>>>(ctx, wob, bo, (float*)d_out);
}